// Round 14
// baseline (162.955 us; speedup 1.0000x reference)
//
#include <hip/hip_runtime.h>

#define FDIM 128
#define HDIM 64
#define MSIZE 64
#define IMG_W 56
#define IMG_H 56
#define NPIX (IMG_W * IMG_H)
#define NB 8
#define NPTS 65536

typedef _Float16 f16x8 __attribute__((ext_vector_type(8)));
typedef __fp16 hf16x2 __attribute__((ext_vector_type(2)));   // return type of cvt_pkrtz
typedef float f32x4 __attribute__((ext_vector_type(4)));

// d_ws layout:
//   [0, 32768)       : W1 fragments fp16 (8kt*4nt*64lane*8); kt 0..3 = image, 4..7 = fourier
//   [32768, 40960)   : W2 fragments
//   [40960, 49152)   : W3 fragments
//   [49152, 49920)   : Bg SoA  (Bx[64], By[64], Bz[64] fp32)
//   [50176, +3.2MB)  : G = feats x W1_img  (B, H*W, C64) fp16
#define W2_OFF 16384   // in halves
#define W3_OFF 20480
#define BG_OFF 49152   // bytes
#define G_BYTE_OFF 50176

__device__ __forceinline__ void lds_fence() {
    __asm__ volatile("s_waitcnt lgkmcnt(0)" ::: "memory");
}

// ---- pack kernel (13 blocks): W1/W2/W3 fragments + Bg SoA (R13-verified math) ----
__global__ __launch_bounds__(256) void pack_kernel(const float* __restrict__ W1,
                                                   const float* __restrict__ W2,
                                                   const float* __restrict__ W3,
                                                   const float* __restrict__ Bg,
                                                   _Float16* __restrict__ ws) {
    if (blockIdx.x < 12) {
        const int t = blockIdx.x * 256 + threadIdx.x;  // 0..3071
        const int l = t & 63;
        const int q = l >> 4;
        const int col = l & 15;
        const int frag = t >> 6;  // 0..47
        if (frag < 32) {
            const int kt = frag >> 2, nt = frag & 3;
#pragma unroll
            for (int j = 0; j < 8; ++j) {
                int k = kt * 32 + q * 8 + j;
                int row = (k < 128) ? k : (128 + (k & 1) * 64 + ((k - 128) >> 1));
                ws[((size_t)(frag * 64 + l)) * 8 + j] = (_Float16)W1[row * HDIM + nt * 16 + col];
            }
        } else if (frag < 40) {
            const int f2 = frag - 32;
            const int kt = f2 >> 2, nt = f2 & 3;
#pragma unroll
            for (int j = 0; j < 8; ++j) {
                int row = kt * 32 + q * 8 + j;
                ws[W2_OFF + ((size_t)(f2 * 64 + l)) * 8 + j] = (_Float16)W2[row * HDIM + nt * 16 + col];
            }
        } else {
            const int f3 = frag - 40;
            const int kt = f3 >> 2, nt = f3 & 3;
#pragma unroll
            for (int j = 0; j < 8; ++j) {
                int row = kt * 32 + q * 8 + j;
                ws[W3_OFF + ((size_t)(f3 * 64 + l)) * 8 + j] = (_Float16)W3[row * HDIM + nt * 16 + col];
            }
        }
    } else {
        const int t = threadIdx.x;
        if (t < MSIZE) {
            float* bgs = (float*)((char*)ws + BG_OFF);
            bgs[t]       = Bg[t * 3 + 0];
            bgs[64 + t]  = Bg[t * 3 + 1];
            bgs[128 + t] = Bg[t * 3 + 2];
        }
    }
}

// ---- fused transpose+GEMM: G[pixel] = W1_img^T . feats[pixel], no ft intermediate ----
// 392 blocks x 4 waves; wave handles one 16px tile. A-frags assembled directly from
// fp32 CHW feats (lane l: A[m=l&15][k=q*8+j] = feats[k*NPIX + pbase + (l&15)]).
__global__ __launch_bounds__(256, 4) void feat2g(const float* __restrict__ in,
                                                 const _Float16* __restrict__ ws,
                                                 _Float16* __restrict__ Gp) {
    const int tid = threadIdx.x;
    const int wid = tid >> 6;
    const int l   = tid & 63;
    const int q   = l >> 4;
    const int col = l & 15;
    const int T = blockIdx.x * 4 + wid;       // 0..1567
    const int b = T / (NPIX / 16);
    const int tile = T % (NPIX / 16);
    const int pbase = tile * 16;
    const float* src = in + (size_t)b * FDIM * NPIX;
    const f32x4 zero4 = {0.0f, 0.0f, 0.0f, 0.0f};
    f32x4 acc[4];
#pragma unroll
    for (int nt = 0; nt < 4; ++nt) acc[nt] = zero4;
#pragma unroll
    for (int kt = 0; kt < 4; ++kt) {
        union { f16x8 v; hf16x2 h[4]; } af;
#pragma unroll
        for (int jj = 0; jj < 4; ++jj) {
            float v0 = src[(size_t)(kt * 32 + q * 8 + 2 * jj)     * NPIX + pbase + col];
            float v1 = src[(size_t)(kt * 32 + q * 8 + 2 * jj + 1) * NPIX + pbase + col];
            af.h[jj] = __builtin_amdgcn_cvt_pkrtz(v0, v1);   // same RTZ as R13's ft path
        }
#pragma unroll
        for (int nt = 0; nt < 4; ++nt) {
            f16x8 bf = *(const f16x8*)(ws + ((size_t)((kt * 4 + nt) * 64 + l)) * 8);
            acc[nt] = __builtin_amdgcn_mfma_f32_16x16x32_f16(af.v, bf, acc[nt], 0, 0, 0);
        }
    }
    // C/D: row = q*4+r (pixel), col = l&15 (n)  [R13-verified]
#pragma unroll
    for (int nt = 0; nt < 4; ++nt)
#pragma unroll
        for (int r = 0; r < 4; ++r)
            Gp[((size_t)(b * NPIX + pbase + q * 4 + r)) * HDIM + nt * 16 + col]
                = (_Float16)acc[nt][r];
}

// -------- per-group state --------
struct Rec {
    float w0[2], w1[2], w2[2], w3[2];
    int   i0[2], i1[2], i2[2], i3[2];   // corner offsets into G (units of HDIM halves)
    float qx[2], qy[2], qz[2];
};

__device__ __forceinline__ void phaseF(f32x4 acc[2][4], const _Float16* __restrict__ w1l,
                                       const float* __restrict__ bgs, const Rec& R,
                                       int q, int l) {
#pragma unroll
    for (int ktf = 0; ktf < 4; ++ktf) {
        const f32x4 bgx = *(const f32x4*)(bgs + ktf * 16 + q * 4);
        const f32x4 bgy = *(const f32x4*)(bgs + 64 + ktf * 16 + q * 4);
        const f32x4 bgz = *(const f32x4*)(bgs + 128 + ktf * 16 + q * 4);
        f16x8 bf[4];
#pragma unroll
        for (int nt = 0; nt < 4; ++nt)
            bf[nt] = *(const f16x8*)(w1l + ((size_t)((ktf * 4 + nt) * 64 + l)) * 8);
#pragma unroll
        for (int mt = 0; mt < 2; ++mt) {
            union { f16x8 v; hf16x2 h[4]; } af;
#pragma unroll
            for (int i = 0; i < 4; ++i) {
                float t = bgx[i] * R.qx[mt] + bgy[i] * R.qy[mt] + bgz[i] * R.qz[mt];
                float tf = __builtin_amdgcn_fractf(t);
                af.h[i] = __builtin_amdgcn_cvt_pkrtz(__builtin_amdgcn_sinf(tf),
                                                     __builtin_amdgcn_cosf(tf));
            }
#pragma unroll
            for (int nt = 0; nt < 4; ++nt)
                acc[mt][nt] = __builtin_amdgcn_mfma_f32_16x16x32_f16(af.v, bf[nt], acc[mt][nt], 0, 0, 0);
        }
    }
}

// tail: G-blend fused into layer-2 A assembly (h1 = relu(fourier+b1 + blend(G)))
__device__ __forceinline__ void mlp_tail2(f32x4 acc[2][4], _Float16* __restrict__ Ah,
                                          const _Float16* __restrict__ wfrag,
                                          const _Float16* __restrict__ Gp,
                                          const Rec& R,
                                          const float* __restrict__ b1,
                                          const float* __restrict__ b2,
                                          const float* __restrict__ b3,
                                          const float* __restrict__ W4,
                                          const float* __restrict__ b4,
                                          float* __restrict__ out, int outbase,
                                          int q, int col, int l) {
    const f32x4 zero4 = {0.0f, 0.0f, 0.0f, 0.0f};
    // issue all 16 G gathers now (consumed after the fence; long issue-to-use distance)
    f16x8 g[2][2][4];
#pragma unroll
    for (int ktl = 0; ktl < 2; ++ktl)
#pragma unroll
        for (int mt = 0; mt < 2; ++mt) {
            const int co = ktl * 32 + q * 8;
            g[ktl][mt][0] = *(const f16x8*)(Gp + R.i0[mt] + co);
            g[ktl][mt][1] = *(const f16x8*)(Gp + R.i1[mt] + co);
            g[ktl][mt][2] = *(const f16x8*)(Gp + R.i2[mt] + co);
            g[ktl][mt][3] = *(const f16x8*)(Gp + R.i3[mt] + co);
        }
    f16x8 bfW[8];
#pragma unroll
    for (int f = 0; f < 8; ++f)
        bfW[f] = *(const f16x8*)(wfrag + W2_OFF + ((size_t)(f * 64 + l)) * 8);

    _Float16 wh[2][4];
#pragma unroll
    for (int mt = 0; mt < 2; ++mt) {
        wh[mt][0] = (_Float16)R.w0[mt]; wh[mt][1] = (_Float16)R.w1[mt];
        wh[mt][2] = (_Float16)R.w2[mt]; wh[mt][3] = (_Float16)R.w3[mt];
    }

    // L1 epilogue: fourier acc + b1, PRE-relu (img part added at layer-2 read)
    float bb[4];
#pragma unroll
    for (int nt = 0; nt < 4; ++nt) bb[nt] = b1[nt * 16 + col];
#pragma unroll
    for (int mt = 0; mt < 2; ++mt)
#pragma unroll
        for (int nt = 0; nt < 4; ++nt)
#pragma unroll
            for (int r = 0; r < 4; ++r)
                Ah[(mt * 16 + q * 4 + r) * 72 + nt * 16 + col]
                    = (_Float16)(acc[mt][nt][r] + bb[nt]);
    lds_fence();

    // layer 2, fused h1 assembly: af = relu(Ah + Σ wc*G[corner_c])
#pragma unroll
    for (int mt = 0; mt < 2; ++mt)
#pragma unroll
        for (int nt = 0; nt < 4; ++nt) acc[mt][nt] = zero4;
#pragma unroll
    for (int ktl = 0; ktl < 2; ++ktl)
#pragma unroll
        for (int mt = 0; mt < 2; ++mt) {
            f16x8 af = *(const f16x8*)(&Ah[(mt * 16 + col) * 72 + ktl * 32 + q * 8]);
            af = af + g[ktl][mt][0] * wh[mt][0] + g[ktl][mt][1] * wh[mt][1]
                    + g[ktl][mt][2] * wh[mt][2] + g[ktl][mt][3] * wh[mt][3];
#pragma unroll
            for (int j = 0; j < 8; ++j)
                af[j] = af[j] > (_Float16)0.0f ? af[j] : (_Float16)0.0f;
#pragma unroll
            for (int nt = 0; nt < 4; ++nt)
                acc[mt][nt] = __builtin_amdgcn_mfma_f32_16x16x32_f16(af, bfW[ktl * 4 + nt], acc[mt][nt], 0, 0, 0);
        }

    // prefetch W3 while layer-2 MFMAs drain
#pragma unroll
    for (int f = 0; f < 8; ++f)
        bfW[f] = *(const f16x8*)(wfrag + W3_OFF + ((size_t)(f * 64 + l)) * 8);

    lds_fence();
#pragma unroll
    for (int nt = 0; nt < 4; ++nt) bb[nt] = b2[nt * 16 + col];
#pragma unroll
    for (int mt = 0; mt < 2; ++mt)
#pragma unroll
        for (int nt = 0; nt < 4; ++nt)
#pragma unroll
            for (int r = 0; r < 4; ++r) {
                float hv = fmaxf(acc[mt][nt][r] + bb[nt], 0.0f);
                Ah[(mt * 16 + q * 4 + r) * 72 + nt * 16 + col] = (_Float16)hv;
            }
    lds_fence();

    // layer 3
#pragma unroll
    for (int mt = 0; mt < 2; ++mt)
#pragma unroll
        for (int nt = 0; nt < 4; ++nt) acc[mt][nt] = zero4;
#pragma unroll
    for (int ktl = 0; ktl < 2; ++ktl)
#pragma unroll
        for (int mt = 0; mt < 2; ++mt) {
            f16x8 af = *(const f16x8*)(&Ah[(mt * 16 + col) * 72 + ktl * 32 + q * 8]);
#pragma unroll
            for (int nt = 0; nt < 4; ++nt)
                acc[mt][nt] = __builtin_amdgcn_mfma_f32_16x16x32_f16(af, bfW[ktl * 4 + nt], acc[mt][nt], 0, 0, 0);
        }

    // layer 4
    float b3v[4], w4v[4];
#pragma unroll
    for (int nt = 0; nt < 4; ++nt) {
        b3v[nt] = b3[nt * 16 + col];
        w4v[nt] = W4[nt * 16 + col];
    }
    const float b4v = b4[0];
#pragma unroll
    for (int mt = 0; mt < 2; ++mt)
#pragma unroll
        for (int r = 0; r < 4; ++r) {
            float p = 0.0f;
#pragma unroll
            for (int nt = 0; nt < 4; ++nt)
                p = fmaf(fmaxf(acc[mt][nt][r] + b3v[nt], 0.0f), w4v[nt], p);
            p += __shfl_xor(p, 1);
            p += __shfl_xor(p, 2);
            p += __shfl_xor(p, 4);
            p += __shfl_xor(p, 8);
            if (col == 0) out[outbase + mt * 16 + q * 4 + r] = p + b4v;
        }
    lds_fence();   // Ah reads done before next group's epilogue overwrites
}

// -------- decoder v8b: R13 structure, occupancy bound raised to 4 blocks/CU --------
__global__ __launch_bounds__(256, 4) void decoder_mfma8(
    const _Float16* __restrict__ Gp,   // (B, HW, 64) fp16 precomputed layer-1 img part
    const float* __restrict__ points,
    const float* __restrict__ Kmat, const float* __restrict__ Rt,
    const _Float16* __restrict__ wfrag,
    const float* __restrict__ b1, const float* __restrict__ b2,
    const float* __restrict__ b3,
    const float* __restrict__ W4, const float* __restrict__ b4,
    float* __restrict__ out) {
    __shared__ _Float16 w1l[8192];           // 16384 B: fourier W1 fragments (kt 4..7)
    __shared__ _Float16 lds[4 * 32 * 72];    // 18432 B: per-wave A/H tiles
    const int tid = threadIdx.x;
    const int wid = tid >> 6;
    const int l   = tid & 63;
    const int q   = l >> 4;
    const int col = l & 15;
    const int b     = blockIdx.x & 7;            // XCD swizzle
    const int grp   = blockIdx.x >> 3;           // 0..255 (2048 blocks)
    const int wbase = b * NPTS + grp * 256 + wid * 64;   // 64 points per wave
    _Float16* Ah = lds + wid * 32 * 72;
    const float* bgs = (const float*)((const char*)wfrag + BG_OFF);

    // ---- stage fourier W1 fragments (frag 16..31) to LDS ----
#pragma unroll
    for (int i = 0; i < 4; ++i)
        ((f16x8*)w1l)[i * 256 + tid] = ((const f16x8*)(wfrag + 8192))[i * 256 + tid];

    // ---- every lane projects its own point (lanes 0-31 -> group0, 32-63 -> group1) ----
    const int gid = wbase + l;
    const float px = points[(size_t)gid * 3 + 0];
    const float py = points[(size_t)gid * 3 + 1];
    const float pz = points[(size_t)gid * 3 + 2];
    const float* rt = Rt + b * 12;
    const float* km = Kmat + b * 9;
    float cx = rt[0] * px + rt[1] * py + rt[2]  * pz + rt[3];
    float cy = rt[4] * px + rt[5] * py + rt[6]  * pz + rt[7];
    float cz = rt[8] * px + rt[9] * py + rt[10] * pz + rt[11];
    float ix = km[0] * cx + km[1] * cy + km[2] * cz;
    float iy = km[3] * cx + km[4] * cy + km[5] * cz;
    float iz = km[6] * cx + km[7] * cy + km[8] * cz;
    float z  = iz + 1e-8f;
    float u  = ix / z;
    float v  = iy / z;
    float valid = (iz > 0.0f) ? 1.0f : 0.0f;
    float u_norm = (2.0f * u + 1.0f) / (float)IMG_W - 1.0f;
    float v_norm = (2.0f * v + 1.0f) / (float)IMG_H - 1.0f;
    float x = ((u_norm + 1.0f) * (float)IMG_W - 1.0f) * 0.5f;
    float y = ((v_norm + 1.0f) * (float)IMG_H - 1.0f) * 0.5f;
    float x0f = floorf(x), y0f = floorf(y);
    float wx1 = x - x0f, wy1 = y - y0f;
    float wx0 = 1.0f - wx1, wy0 = 1.0f - wy1;
    int x0 = (int)x0f, y0 = (int)y0f;
    int x1 = x0 + 1, y1 = y0 + 1;
    int x0c = x0 < 0 ? 0 : (x0 > IMG_W - 1 ? IMG_W - 1 : x0);
    int x1c = x1 < 0 ? 0 : (x1 > IMG_W - 1 ? IMG_W - 1 : x1);
    int y0c = y0 < 0 ? 0 : (y0 > IMG_H - 1 ? IMG_H - 1 : y0);
    int y1c = y1 < 0 ? 0 : (y1 > IMG_H - 1 ? IMG_H - 1 : y1);
    float mx0 = (x0 >= 0 && x0 < IMG_W) ? 1.0f : 0.0f;
    float mx1 = (x1 >= 0 && x1 < IMG_W) ? 1.0f : 0.0f;
    float my0 = (y0 >= 0 && y0 < IMG_H) ? 1.0f : 0.0f;
    float my1 = (y1 >= 0 && y1 < IMG_H) ? 1.0f : 0.0f;
    const int pb = b * NPIX;
    float r_w00 = wx0 * wy0 * mx0 * my0 * valid;
    float r_w10 = wx1 * wy0 * mx1 * my0 * valid;
    float r_w01 = wx0 * wy1 * mx0 * my1 * valid;
    float r_w11 = wx1 * wy1 * mx1 * my1 * valid;
    int r_i00 = (pb + y0c * IMG_W + x0c) * HDIM;
    int r_i10 = (pb + y0c * IMG_W + x1c) * HDIM;
    int r_i01 = (pb + y1c * IMG_W + x0c) * HDIM;
    int r_i11 = (pb + y1c * IMG_W + x1c) * HDIM;

    f32x4 acc[2][4];
    const f32x4 zero4 = {0.0f, 0.0f, 0.0f, 0.0f};

    // ====== group 0 ======
    {
        Rec R0;
#pragma unroll
        for (int mt = 0; mt < 2; ++mt) {
            const int src = mt * 16 + col;
            R0.w0[mt] = __shfl(r_w00, src);
            R0.w1[mt] = __shfl(r_w10, src);
            R0.w2[mt] = __shfl(r_w01, src);
            R0.w3[mt] = __shfl(r_w11, src);
            R0.i0[mt] = __shfl(r_i00, src);
            R0.i1[mt] = __shfl(r_i10, src);
            R0.i2[mt] = __shfl(r_i01, src);
            R0.i3[mt] = __shfl(r_i11, src);
            R0.qx[mt] = __shfl(px, src);
            R0.qy[mt] = __shfl(py, src);
            R0.qz[mt] = __shfl(pz, src);
        }
        __syncthreads();   // w1l staged
#pragma unroll
        for (int mt = 0; mt < 2; ++mt)
#pragma unroll
            for (int nt = 0; nt < 4; ++nt) acc[mt][nt] = zero4;
        phaseF(acc, w1l, bgs, R0, q, l);
        mlp_tail2(acc, Ah, wfrag, Gp, R0, b1, b2, b3, W4, b4, out, wbase, q, col, l);
    }

    __builtin_amdgcn_sched_barrier(0);

    // ====== group 1 ======
    {
        Rec R1;
#pragma unroll
        for (int mt = 0; mt < 2; ++mt) {
            const int src = 32 + mt * 16 + col;
            R1.w0[mt] = __shfl(r_w00, src);
            R1.w1[mt] = __shfl(r_w10, src);
            R1.w2[mt] = __shfl(r_w01, src);
            R1.w3[mt] = __shfl(r_w11, src);
            R1.i0[mt] = __shfl(r_i00, src);
            R1.i1[mt] = __shfl(r_i10, src);
            R1.i2[mt] = __shfl(r_i01, src);
            R1.i3[mt] = __shfl(r_i11, src);
            R1.qx[mt] = __shfl(px, src);
            R1.qy[mt] = __shfl(py, src);
            R1.qz[mt] = __shfl(pz, src);
        }
#pragma unroll
        for (int mt = 0; mt < 2; ++mt)
#pragma unroll
            for (int nt = 0; nt < 4; ++nt) acc[mt][nt] = zero4;
        phaseF(acc, w1l, bgs, R1, q, l);
        mlp_tail2(acc, Ah, wfrag, Gp, R1, b1, b2, b3, W4, b4, out, wbase + 32, q, col, l);
    }
}

// ---------------- fallback: verified R1 pure-VALU kernel ----------------
__global__ __launch_bounds__(64, 2) void decoder_valu(
    const float* __restrict__ feats, const float* __restrict__ points,
    const float* __restrict__ Kmat, const float* __restrict__ Rt,
    const float* __restrict__ Bg,
    const float* __restrict__ W1, const float* __restrict__ b1,
    const float* __restrict__ W2, const float* __restrict__ b2,
    const float* __restrict__ W3, const float* __restrict__ b3,
    const float* __restrict__ W4, const float* __restrict__ b4,
    float* __restrict__ out) {
    __shared__ float hbuf[64 * 65];
    const int tid = threadIdx.x;
    const int b   = blockIdx.x / (NPTS / 64);
    const int gid = blockIdx.x * 64 + tid;
    const float px = points[(size_t)gid * 3 + 0];
    const float py = points[(size_t)gid * 3 + 1];
    const float pz = points[(size_t)gid * 3 + 2];
    const float* rt = Rt + b * 12;
    const float* km = Kmat + b * 9;
    float cx = rt[0] * px + rt[1] * py + rt[2]  * pz + rt[3];
    float cy = rt[4] * px + rt[5] * py + rt[6]  * pz + rt[7];
    float cz = rt[8] * px + rt[9] * py + rt[10] * pz + rt[11];
    float ix = km[0] * cx + km[1] * cy + km[2] * cz;
    float iy = km[3] * cx + km[4] * cy + km[5] * cz;
    float iz = km[6] * cx + km[7] * cy + km[8] * cz;
    float z  = iz + 1e-8f;
    float u  = ix / z, v = iy / z;
    float valid = (iz > 0.0f) ? 1.0f : 0.0f;
    float u_norm = (2.0f * u + 1.0f) / (float)IMG_W - 1.0f;
    float v_norm = (2.0f * v + 1.0f) / (float)IMG_H - 1.0f;
    float x = ((u_norm + 1.0f) * (float)IMG_W - 1.0f) * 0.5f;
    float y = ((v_norm + 1.0f) * (float)IMG_H - 1.0f) * 0.5f;
    float x0f = floorf(x), y0f = floorf(y);
    float wx1 = x - x0f, wy1 = y - y0f;
    float wx0 = 1.0f - wx1, wy0 = 1.0f - wy1;
    int x0 = (int)x0f, y0 = (int)y0f;
    int x1 = x0 + 1, y1 = y0 + 1;
    int x0c = x0 < 0 ? 0 : (x0 > IMG_W - 1 ? IMG_W - 1 : x0);
    int x1c = x1 < 0 ? 0 : (x1 > IMG_W - 1 ? IMG_W - 1 : x1);
    int y0c = y0 < 0 ? 0 : (y0 > IMG_H - 1 ? IMG_H - 1 : y0);
    int y1c = y1 < 0 ? 0 : (y1 > IMG_H - 1 ? IMG_H - 1 : y1);
    float mx0 = (x0 >= 0 && x0 < IMG_W) ? 1.0f : 0.0f;
    float mx1 = (x1 >= 0 && x1 < IMG_W) ? 1.0f : 0.0f;
    float my0 = (y0 >= 0 && y0 < IMG_H) ? 1.0f : 0.0f;
    float my1 = (y1 >= 0 && y1 < IMG_H) ? 1.0f : 0.0f;
    float w00 = wx0 * wy0 * mx0 * my0 * valid;
    float w10 = wx1 * wy0 * mx1 * my0 * valid;
    float w01 = wx0 * wy1 * mx0 * my1 * valid;
    float w11 = wx1 * wy1 * mx1 * my1 * valid;
    float h[HDIM];
#pragma unroll
    for (int j = 0; j < HDIM; ++j) h[j] = b1[j];
    const float* fb = feats + (size_t)b * FDIM * NPIX;
    const int p00 = y0c * IMG_W + x0c, p10 = y0c * IMG_W + x1c;
    const int p01 = y1c * IMG_W + x0c, p11 = y1c * IMG_W + x1c;
#pragma unroll 1
    for (int c = 0; c < FDIM; ++c) {
        const float* fp = fb + (size_t)c * NPIX;
        float fv = w00 * fp[p00] + w10 * fp[p10] + w01 * fp[p01] + w11 * fp[p11];
        const float* wr = W1 + (size_t)c * HDIM;
#pragma unroll
        for (int j = 0; j < HDIM; ++j) h[j] = fmaf(fv, wr[j], h[j]);
    }
#pragma unroll 1
    for (int m = 0; m < MSIZE; ++m) {
        float t = Bg[m * 3 + 0] * px + Bg[m * 3 + 1] * py + Bg[m * 3 + 2] * pz;
        float tf = t - floorf(t);
        float s = __builtin_amdgcn_sinf(tf);
        float c = __builtin_amdgcn_cosf(tf);
        const float* wsn = W1 + (size_t)(FDIM + m) * HDIM;
        const float* wcs = W1 + (size_t)(FDIM + MSIZE + m) * HDIM;
#pragma unroll
        for (int j = 0; j < HDIM; ++j)
            h[j] = fmaf(s, wsn[j], fmaf(c, wcs[j], h[j]));
    }
    float* myh = &hbuf[tid * 65];
#pragma unroll
    for (int j = 0; j < HDIM; ++j) myh[j] = fmaxf(h[j], 0.0f);
    float h2[HDIM];
#pragma unroll
    for (int j = 0; j < HDIM; ++j) h2[j] = b2[j];
#pragma unroll 1
    for (int i = 0; i < HDIM; ++i) {
        float hi = myh[i];
        const float* wr = W2 + (size_t)i * HDIM;
#pragma unroll
        for (int j = 0; j < HDIM; ++j) h2[j] = fmaf(hi, wr[j], h2[j]);
    }
#pragma unroll
    for (int j = 0; j < HDIM; ++j) myh[j] = fmaxf(h2[j], 0.0f);
#pragma unroll
    for (int j = 0; j < HDIM; ++j) h[j] = b3[j];
#pragma unroll 1
    for (int i = 0; i < HDIM; ++i) {
        float hi = myh[i];
        const float* wr = W3 + (size_t)i * HDIM;
#pragma unroll
        for (int j = 0; j < HDIM; ++j) h[j] = fmaf(hi, wr[j], h[j]);
    }
    float acc = b4[0];
#pragma unroll
    for (int j = 0; j < HDIM; ++j) acc = fmaf(fmaxf(h[j], 0.0f), W4[j], acc);
    out[gid] = acc;
}

extern "C" void kernel_launch(void* const* d_in, const int* in_sizes, int n_in,
                              void* d_out, int out_size, void* d_ws, size_t ws_size,
                              hipStream_t stream) {
    const float* feats = (const float*)d_in[0];
    const float* pts   = (const float*)d_in[1];
    const float* k     = (const float*)d_in[2];
    const float* rt    = (const float*)d_in[3];
    const float* Bg    = (const float*)d_in[4];
    const float* W1    = (const float*)d_in[5];
    const float* b1    = (const float*)d_in[6];
    const float* W2    = (const float*)d_in[7];
    const float* b2    = (const float*)d_in[8];
    const float* W3    = (const float*)d_in[9];
    const float* b3    = (const float*)d_in[10];
    const float* W4    = (const float*)d_in[11];
    const float* b4    = (const float*)d_in[12];
    float* out = (float*)d_out;

    const size_t gBytes = (size_t)NB * NPIX * HDIM * sizeof(_Float16);
    const size_t need = G_BYTE_OFF + gBytes;   // ~3.26 MB

    if (ws_size >= need) {
        _Float16* wf = (_Float16*)d_ws;
        _Float16* Gp = (_Float16*)((char*)d_ws + G_BYTE_OFF);
        pack_kernel<<<13, 256, 0, stream>>>(W1, W2, W3, Bg, wf);
        feat2g<<<NB * NPIX / 16 / 4, 256, 0, stream>>>(feats, wf, Gp);
        decoder_mfma8<<<NB * NPTS / 256, 256, 0, stream>>>(Gp, pts, k, rt, wf,
                                                           b1, b2, b3, W4, b4, out);
    } else {
        decoder_valu<<<NB * NPTS / 64, 64, 0, stream>>>(feats, pts, k, rt, Bg,
                                                        W1, b1, W2, b2, W3, b3, W4, b4, out);
    }
}

// Round 15
// 150.785 us; speedup vs baseline: 1.0807x; 1.0807x over previous
//
#include <hip/hip_runtime.h>

#define FDIM 128
#define HDIM 64
#define MSIZE 64
#define IMG_W 56
#define IMG_H 56
#define NPIX (IMG_W * IMG_H)
#define NB 8
#define NPTS 65536

typedef _Float16 f16x8 __attribute__((ext_vector_type(8)));
typedef __fp16 hf16x2 __attribute__((ext_vector_type(2)));   // return type of cvt_pkrtz
typedef float f32x4 __attribute__((ext_vector_type(4)));

// d_ws layout:
//   [0, 32768)       : W1 fragments fp16 (8kt*4nt*64lane*8); kt 0..3 = image, 4..7 = fourier
//   [32768, 40960)   : W2 fragments
//   [40960, 49152)   : W3 fragments
//   [49152, 49920)   : Bg SoA  (Bx[64], By[64], Bz[64] fp32)
//   [50176, +3.2MB)  : G = feats x W1_img  (B, H*W, C64) fp16
#define W2_OFF 16384   // in halves
#define W3_OFF 20480
#define BG_OFF 49152   // bytes
#define G_BYTE_OFF 50176

__device__ __forceinline__ void lds_fence() {
    __asm__ volatile("s_waitcnt lgkmcnt(0)" ::: "memory");
}

// ---- pack kernel (13 blocks): W1/W2/W3 fragments + Bg SoA (R13-verified math) ----
__global__ __launch_bounds__(256) void pack_kernel(const float* __restrict__ W1,
                                                   const float* __restrict__ W2,
                                                   const float* __restrict__ W3,
                                                   const float* __restrict__ Bg,
                                                   _Float16* __restrict__ ws) {
    if (blockIdx.x < 12) {
        const int t = blockIdx.x * 256 + threadIdx.x;  // 0..3071
        const int l = t & 63;
        const int q = l >> 4;
        const int col = l & 15;
        const int frag = t >> 6;  // 0..47
        if (frag < 32) {
            const int kt = frag >> 2, nt = frag & 3;
#pragma unroll
            for (int j = 0; j < 8; ++j) {
                int k = kt * 32 + q * 8 + j;
                int row = (k < 128) ? k : (128 + (k & 1) * 64 + ((k - 128) >> 1));
                ws[((size_t)(frag * 64 + l)) * 8 + j] = (_Float16)W1[row * HDIM + nt * 16 + col];
            }
        } else if (frag < 40) {
            const int f2 = frag - 32;
            const int kt = f2 >> 2, nt = f2 & 3;
#pragma unroll
            for (int j = 0; j < 8; ++j) {
                int row = kt * 32 + q * 8 + j;
                ws[W2_OFF + ((size_t)(f2 * 64 + l)) * 8 + j] = (_Float16)W2[row * HDIM + nt * 16 + col];
            }
        } else {
            const int f3 = frag - 40;
            const int kt = f3 >> 2, nt = f3 & 3;
#pragma unroll
            for (int j = 0; j < 8; ++j) {
                int row = kt * 32 + q * 8 + j;
                ws[W3_OFF + ((size_t)(f3 * 64 + l)) * 8 + j] = (_Float16)W3[row * HDIM + nt * 16 + col];
            }
        }
    } else {
        const int t = threadIdx.x;
        if (t < MSIZE) {
            float* bgs = (float*)((char*)ws + BG_OFF);
            bgs[t]       = Bg[t * 3 + 0];
            bgs[64 + t]  = Bg[t * 3 + 1];
            bgs[128 + t] = Bg[t * 3 + 2];
        }
    }
}

// ---- fused transpose+GEMM (R14-verified): G[pixel] = W1_img^T . feats[pixel] ----
__global__ __launch_bounds__(256, 4) void feat2g(const float* __restrict__ in,
                                                 const _Float16* __restrict__ ws,
                                                 _Float16* __restrict__ Gp) {
    const int tid = threadIdx.x;
    const int wid = tid >> 6;
    const int l   = tid & 63;
    const int q   = l >> 4;
    const int col = l & 15;
    const int T = blockIdx.x * 4 + wid;       // 0..1567
    const int b = T / (NPIX / 16);
    const int tile = T % (NPIX / 16);
    const int pbase = tile * 16;
    const float* src = in + (size_t)b * FDIM * NPIX;
    const f32x4 zero4 = {0.0f, 0.0f, 0.0f, 0.0f};
    f32x4 acc[4];
#pragma unroll
    for (int nt = 0; nt < 4; ++nt) acc[nt] = zero4;
#pragma unroll
    for (int kt = 0; kt < 4; ++kt) {
        union { f16x8 v; hf16x2 h[4]; } af;
#pragma unroll
        for (int jj = 0; jj < 4; ++jj) {
            float v0 = src[(size_t)(kt * 32 + q * 8 + 2 * jj)     * NPIX + pbase + col];
            float v1 = src[(size_t)(kt * 32 + q * 8 + 2 * jj + 1) * NPIX + pbase + col];
            af.h[jj] = __builtin_amdgcn_cvt_pkrtz(v0, v1);
        }
#pragma unroll
        for (int nt = 0; nt < 4; ++nt) {
            f16x8 bf = *(const f16x8*)(ws + ((size_t)((kt * 4 + nt) * 64 + l)) * 8);
            acc[nt] = __builtin_amdgcn_mfma_f32_16x16x32_f16(af.v, bf, acc[nt], 0, 0, 0);
        }
    }
#pragma unroll
    for (int nt = 0; nt < 4; ++nt)
#pragma unroll
        for (int r = 0; r < 4; ++r)
            Gp[((size_t)(b * NPIX + pbase + q * 4 + r)) * HDIM + nt * 16 + col]
                = (_Float16)acc[nt][r];
}

// -------- per-group state --------
struct Rec {
    float w0[2], w1[2], w2[2], w3[2];
    int   i0[2], i1[2], i2[2], i3[2];   // corner offsets into G (units of HDIM halves)
    float qx[2], qy[2], qz[2];
};

__device__ __forceinline__ void phaseF(f32x4 acc[2][4], const _Float16* __restrict__ w1l,
                                       const float* __restrict__ bgs, const Rec& R,
                                       int q, int l) {
#pragma unroll
    for (int ktf = 0; ktf < 4; ++ktf) {
        const f32x4 bgx = *(const f32x4*)(bgs + ktf * 16 + q * 4);
        const f32x4 bgy = *(const f32x4*)(bgs + 64 + ktf * 16 + q * 4);
        const f32x4 bgz = *(const f32x4*)(bgs + 128 + ktf * 16 + q * 4);
        f16x8 bf[4];
#pragma unroll
        for (int nt = 0; nt < 4; ++nt)
            bf[nt] = *(const f16x8*)(w1l + ((size_t)((ktf * 4 + nt) * 64 + l)) * 8);
#pragma unroll
        for (int mt = 0; mt < 2; ++mt) {
            union { f16x8 v; hf16x2 h[4]; } af;
#pragma unroll
            for (int i = 0; i < 4; ++i) {
                float t = bgx[i] * R.qx[mt] + bgy[i] * R.qy[mt] + bgz[i] * R.qz[mt];
                float tf = __builtin_amdgcn_fractf(t);
                af.h[i] = __builtin_amdgcn_cvt_pkrtz(__builtin_amdgcn_sinf(tf),
                                                     __builtin_amdgcn_cosf(tf));
            }
#pragma unroll
            for (int nt = 0; nt < 4; ++nt)
                acc[mt][nt] = __builtin_amdgcn_mfma_f32_16x16x32_f16(af.v, bf[nt], acc[mt][nt], 0, 0, 0);
        }
    }
}

// tail: G-blend fused into layer-2 A assembly (h1 = relu(fourier+b1 + blend(G)))
__device__ __forceinline__ void mlp_tail2(f32x4 acc[2][4], _Float16* __restrict__ Ah,
                                          const _Float16* __restrict__ wfrag,
                                          const _Float16* __restrict__ Gp,
                                          const Rec& R,
                                          const float* __restrict__ b1,
                                          const float* __restrict__ b2,
                                          const float* __restrict__ b3,
                                          const float* __restrict__ W4,
                                          const float* __restrict__ b4,
                                          float* __restrict__ out, int outbase,
                                          int q, int col, int l) {
    const f32x4 zero4 = {0.0f, 0.0f, 0.0f, 0.0f};
    // issue all 16 G gathers now (consumed after the fence; long issue-to-use distance)
    f16x8 g[2][2][4];
#pragma unroll
    for (int ktl = 0; ktl < 2; ++ktl)
#pragma unroll
        for (int mt = 0; mt < 2; ++mt) {
            const int co = ktl * 32 + q * 8;
            g[ktl][mt][0] = *(const f16x8*)(Gp + R.i0[mt] + co);
            g[ktl][mt][1] = *(const f16x8*)(Gp + R.i1[mt] + co);
            g[ktl][mt][2] = *(const f16x8*)(Gp + R.i2[mt] + co);
            g[ktl][mt][3] = *(const f16x8*)(Gp + R.i3[mt] + co);
        }
    f16x8 bfW[8];
#pragma unroll
    for (int f = 0; f < 8; ++f)
        bfW[f] = *(const f16x8*)(wfrag + W2_OFF + ((size_t)(f * 64 + l)) * 8);

    _Float16 wh[2][4];
#pragma unroll
    for (int mt = 0; mt < 2; ++mt) {
        wh[mt][0] = (_Float16)R.w0[mt]; wh[mt][1] = (_Float16)R.w1[mt];
        wh[mt][2] = (_Float16)R.w2[mt]; wh[mt][3] = (_Float16)R.w3[mt];
    }

    // L1 epilogue: fourier acc + b1, PRE-relu (img part added at layer-2 read)
    float bb[4];
#pragma unroll
    for (int nt = 0; nt < 4; ++nt) bb[nt] = b1[nt * 16 + col];
#pragma unroll
    for (int mt = 0; mt < 2; ++mt)
#pragma unroll
        for (int nt = 0; nt < 4; ++nt)
#pragma unroll
            for (int r = 0; r < 4; ++r)
                Ah[(mt * 16 + q * 4 + r) * 72 + nt * 16 + col]
                    = (_Float16)(acc[mt][nt][r] + bb[nt]);
    lds_fence();

    // layer 2, fused h1 assembly: af = relu(Ah + Σ wc*G[corner_c])
#pragma unroll
    for (int mt = 0; mt < 2; ++mt)
#pragma unroll
        for (int nt = 0; nt < 4; ++nt) acc[mt][nt] = zero4;
#pragma unroll
    for (int ktl = 0; ktl < 2; ++ktl)
#pragma unroll
        for (int mt = 0; mt < 2; ++mt) {
            f16x8 af = *(const f16x8*)(&Ah[(mt * 16 + col) * 72 + ktl * 32 + q * 8]);
            af = af + g[ktl][mt][0] * wh[mt][0] + g[ktl][mt][1] * wh[mt][1]
                    + g[ktl][mt][2] * wh[mt][2] + g[ktl][mt][3] * wh[mt][3];
#pragma unroll
            for (int j = 0; j < 8; ++j)
                af[j] = af[j] > (_Float16)0.0f ? af[j] : (_Float16)0.0f;
#pragma unroll
            for (int nt = 0; nt < 4; ++nt)
                acc[mt][nt] = __builtin_amdgcn_mfma_f32_16x16x32_f16(af, bfW[ktl * 4 + nt], acc[mt][nt], 0, 0, 0);
        }

    // prefetch W3 while layer-2 MFMAs drain
#pragma unroll
    for (int f = 0; f < 8; ++f)
        bfW[f] = *(const f16x8*)(wfrag + W3_OFF + ((size_t)(f * 64 + l)) * 8);

    lds_fence();
#pragma unroll
    for (int nt = 0; nt < 4; ++nt) bb[nt] = b2[nt * 16 + col];
#pragma unroll
    for (int mt = 0; mt < 2; ++mt)
#pragma unroll
        for (int nt = 0; nt < 4; ++nt)
#pragma unroll
            for (int r = 0; r < 4; ++r) {
                float hv = fmaxf(acc[mt][nt][r] + bb[nt], 0.0f);
                Ah[(mt * 16 + q * 4 + r) * 72 + nt * 16 + col] = (_Float16)hv;
            }
    lds_fence();

    // layer 3
#pragma unroll
    for (int mt = 0; mt < 2; ++mt)
#pragma unroll
        for (int nt = 0; nt < 4; ++nt) acc[mt][nt] = zero4;
#pragma unroll
    for (int ktl = 0; ktl < 2; ++ktl)
#pragma unroll
        for (int mt = 0; mt < 2; ++mt) {
            f16x8 af = *(const f16x8*)(&Ah[(mt * 16 + col) * 72 + ktl * 32 + q * 8]);
#pragma unroll
            for (int nt = 0; nt < 4; ++nt)
                acc[mt][nt] = __builtin_amdgcn_mfma_f32_16x16x32_f16(af, bfW[ktl * 4 + nt], acc[mt][nt], 0, 0, 0);
        }

    // layer 4
    float b3v[4], w4v[4];
#pragma unroll
    for (int nt = 0; nt < 4; ++nt) {
        b3v[nt] = b3[nt * 16 + col];
        w4v[nt] = W4[nt * 16 + col];
    }
    const float b4v = b4[0];
#pragma unroll
    for (int mt = 0; mt < 2; ++mt)
#pragma unroll
        for (int r = 0; r < 4; ++r) {
            float p = 0.0f;
#pragma unroll
            for (int nt = 0; nt < 4; ++nt)
                p = fmaf(fmaxf(acc[mt][nt][r] + b3v[nt], 0.0f), w4v[nt], p);
            p += __shfl_xor(p, 1);
            p += __shfl_xor(p, 2);
            p += __shfl_xor(p, 4);
            p += __shfl_xor(p, 8);
            if (col == 0) out[outbase + mt * 16 + q * 4 + r] = p + b4v;
        }
    lds_fence();   // Ah reads done before next group's epilogue overwrites
}

// -------- decoder v8 (R13-verified config): (256,3), no spill --------
__global__ __launch_bounds__(256, 3) void decoder_mfma8(
    const _Float16* __restrict__ Gp,   // (B, HW, 64) fp16 precomputed layer-1 img part
    const float* __restrict__ points,
    const float* __restrict__ Kmat, const float* __restrict__ Rt,
    const _Float16* __restrict__ wfrag,
    const float* __restrict__ b1, const float* __restrict__ b2,
    const float* __restrict__ b3,
    const float* __restrict__ W4, const float* __restrict__ b4,
    float* __restrict__ out) {
    __shared__ _Float16 w1l[8192];           // 16384 B: fourier W1 fragments (kt 4..7)
    __shared__ _Float16 lds[4 * 32 * 72];    // 18432 B: per-wave A/H tiles
    const int tid = threadIdx.x;
    const int wid = tid >> 6;
    const int l   = tid & 63;
    const int q   = l >> 4;
    const int col = l & 15;
    const int b     = blockIdx.x & 7;            // XCD swizzle
    const int grp   = blockIdx.x >> 3;           // 0..255 (2048 blocks)
    const int wbase = b * NPTS + grp * 256 + wid * 64;   // 64 points per wave
    _Float16* Ah = lds + wid * 32 * 72;
    const float* bgs = (const float*)((const char*)wfrag + BG_OFF);

    // ---- stage fourier W1 fragments (frag 16..31) to LDS ----
#pragma unroll
    for (int i = 0; i < 4; ++i)
        ((f16x8*)w1l)[i * 256 + tid] = ((const f16x8*)(wfrag + 8192))[i * 256 + tid];

    // ---- every lane projects its own point (lanes 0-31 -> group0, 32-63 -> group1) ----
    const int gid = wbase + l;
    const float px = points[(size_t)gid * 3 + 0];
    const float py = points[(size_t)gid * 3 + 1];
    const float pz = points[(size_t)gid * 3 + 2];
    const float* rt = Rt + b * 12;
    const float* km = Kmat + b * 9;
    float cx = rt[0] * px + rt[1] * py + rt[2]  * pz + rt[3];
    float cy = rt[4] * px + rt[5] * py + rt[6]  * pz + rt[7];
    float cz = rt[8] * px + rt[9] * py + rt[10] * pz + rt[11];
    float ix = km[0] * cx + km[1] * cy + km[2] * cz;
    float iy = km[3] * cx + km[4] * cy + km[5] * cz;
    float iz = km[6] * cx + km[7] * cy + km[8] * cz;
    float z  = iz + 1e-8f;
    float u  = ix / z;
    float v  = iy / z;
    float valid = (iz > 0.0f) ? 1.0f : 0.0f;
    float u_norm = (2.0f * u + 1.0f) / (float)IMG_W - 1.0f;
    float v_norm = (2.0f * v + 1.0f) / (float)IMG_H - 1.0f;
    float x = ((u_norm + 1.0f) * (float)IMG_W - 1.0f) * 0.5f;
    float y = ((v_norm + 1.0f) * (float)IMG_H - 1.0f) * 0.5f;
    float x0f = floorf(x), y0f = floorf(y);
    float wx1 = x - x0f, wy1 = y - y0f;
    float wx0 = 1.0f - wx1, wy0 = 1.0f - wy1;
    int x0 = (int)x0f, y0 = (int)y0f;
    int x1 = x0 + 1, y1 = y0 + 1;
    int x0c = x0 < 0 ? 0 : (x0 > IMG_W - 1 ? IMG_W - 1 : x0);
    int x1c = x1 < 0 ? 0 : (x1 > IMG_W - 1 ? IMG_W - 1 : x1);
    int y0c = y0 < 0 ? 0 : (y0 > IMG_H - 1 ? IMG_H - 1 : y0);
    int y1c = y1 < 0 ? 0 : (y1 > IMG_H - 1 ? IMG_H - 1 : y1);
    float mx0 = (x0 >= 0 && x0 < IMG_W) ? 1.0f : 0.0f;
    float mx1 = (x1 >= 0 && x1 < IMG_W) ? 1.0f : 0.0f;
    float my0 = (y0 >= 0 && y0 < IMG_H) ? 1.0f : 0.0f;
    float my1 = (y1 >= 0 && y1 < IMG_H) ? 1.0f : 0.0f;
    const int pb = b * NPIX;
    float r_w00 = wx0 * wy0 * mx0 * my0 * valid;
    float r_w10 = wx1 * wy0 * mx1 * my0 * valid;
    float r_w01 = wx0 * wy1 * mx0 * my1 * valid;
    float r_w11 = wx1 * wy1 * mx1 * my1 * valid;
    int r_i00 = (pb + y0c * IMG_W + x0c) * HDIM;
    int r_i10 = (pb + y0c * IMG_W + x1c) * HDIM;
    int r_i01 = (pb + y1c * IMG_W + x0c) * HDIM;
    int r_i11 = (pb + y1c * IMG_W + x1c) * HDIM;

    f32x4 acc[2][4];
    const f32x4 zero4 = {0.0f, 0.0f, 0.0f, 0.0f};

    // ====== group 0 ======
    {
        Rec R0;
#pragma unroll
        for (int mt = 0; mt < 2; ++mt) {
            const int src = mt * 16 + col;
            R0.w0[mt] = __shfl(r_w00, src);
            R0.w1[mt] = __shfl(r_w10, src);
            R0.w2[mt] = __shfl(r_w01, src);
            R0.w3[mt] = __shfl(r_w11, src);
            R0.i0[mt] = __shfl(r_i00, src);
            R0.i1[mt] = __shfl(r_i10, src);
            R0.i2[mt] = __shfl(r_i01, src);
            R0.i3[mt] = __shfl(r_i11, src);
            R0.qx[mt] = __shfl(px, src);
            R0.qy[mt] = __shfl(py, src);
            R0.qz[mt] = __shfl(pz, src);
        }
        __syncthreads();   // w1l staged
#pragma unroll
        for (int mt = 0; mt < 2; ++mt)
#pragma unroll
            for (int nt = 0; nt < 4; ++nt) acc[mt][nt] = zero4;
        phaseF(acc, w1l, bgs, R0, q, l);
        mlp_tail2(acc, Ah, wfrag, Gp, R0, b1, b2, b3, W4, b4, out, wbase, q, col, l);
    }

    __builtin_amdgcn_sched_barrier(0);

    // ====== group 1 ======
    {
        Rec R1;
#pragma unroll
        for (int mt = 0; mt < 2; ++mt) {
            const int src = 32 + mt * 16 + col;
            R1.w0[mt] = __shfl(r_w00, src);
            R1.w1[mt] = __shfl(r_w10, src);
            R1.w2[mt] = __shfl(r_w01, src);
            R1.w3[mt] = __shfl(r_w11, src);
            R1.i0[mt] = __shfl(r_i00, src);
            R1.i1[mt] = __shfl(r_i10, src);
            R1.i2[mt] = __shfl(r_i01, src);
            R1.i3[mt] = __shfl(r_i11, src);
            R1.qx[mt] = __shfl(px, src);
            R1.qy[mt] = __shfl(py, src);
            R1.qz[mt] = __shfl(pz, src);
        }
#pragma unroll
        for (int mt = 0; mt < 2; ++mt)
#pragma unroll
            for (int nt = 0; nt < 4; ++nt) acc[mt][nt] = zero4;
        phaseF(acc, w1l, bgs, R1, q, l);
        mlp_tail2(acc, Ah, wfrag, Gp, R1, b1, b2, b3, W4, b4, out, wbase + 32, q, col, l);
    }
}

// ---------------- fallback: verified R1 pure-VALU kernel ----------------
__global__ __launch_bounds__(64, 2) void decoder_valu(
    const float* __restrict__ feats, const float* __restrict__ points,
    const float* __restrict__ Kmat, const float* __restrict__ Rt,
    const float* __restrict__ Bg,
    const float* __restrict__ W1, const float* __restrict__ b1,
    const float* __restrict__ W2, const float* __restrict__ b2,
    const float* __restrict__ W3, const float* __restrict__ b3,
    const float* __restrict__ W4, const float* __restrict__ b4,
    float* __restrict__ out) {
    __shared__ float hbuf[64 * 65];
    const int tid = threadIdx.x;
    const int b   = blockIdx.x / (NPTS / 64);
    const int gid = blockIdx.x * 64 + tid;
    const float px = points[(size_t)gid * 3 + 0];
    const float py = points[(size_t)gid * 3 + 1];
    const float pz = points[(size_t)gid * 3 + 2];
    const float* rt = Rt + b * 12;
    const float* km = Kmat + b * 9;
    float cx = rt[0] * px + rt[1] * py + rt[2]  * pz + rt[3];
    float cy = rt[4] * px + rt[5] * py + rt[6]  * pz + rt[7];
    float cz = rt[8] * px + rt[9] * py + rt[10] * pz + rt[11];
    float ix = km[0] * cx + km[1] * cy + km[2] * cz;
    float iy = km[3] * cx + km[4] * cy + km[5] * cz;
    float iz = km[6] * cx + km[7] * cy + km[8] * cz;
    float z  = iz + 1e-8f;
    float u  = ix / z, v = iy / z;
    float valid = (iz > 0.0f) ? 1.0f : 0.0f;
    float u_norm = (2.0f * u + 1.0f) / (float)IMG_W - 1.0f;
    float v_norm = (2.0f * v + 1.0f) / (float)IMG_H - 1.0f;
    float x = ((u_norm + 1.0f) * (float)IMG_W - 1.0f) * 0.5f;
    float y = ((v_norm + 1.0f) * (float)IMG_H - 1.0f) * 0.5f;
    float x0f = floorf(x), y0f = floorf(y);
    float wx1 = x - x0f, wy1 = y - y0f;
    float wx0 = 1.0f - wx1, wy0 = 1.0f - wy1;
    int x0 = (int)x0f, y0 = (int)y0f;
    int x1 = x0 + 1, y1 = y0 + 1;
    int x0c = x0 < 0 ? 0 : (x0 > IMG_W - 1 ? IMG_W - 1 : x0);
    int x1c = x1 < 0 ? 0 : (x1 > IMG_W - 1 ? IMG_W - 1 : x1);
    int y0c = y0 < 0 ? 0 : (y0 > IMG_H - 1 ? IMG_H - 1 : y0);
    int y1c = y1 < 0 ? 0 : (y1 > IMG_H - 1 ? IMG_H - 1 : y1);
    float mx0 = (x0 >= 0 && x0 < IMG_W) ? 1.0f : 0.0f;
    float mx1 = (x1 >= 0 && x1 < IMG_W) ? 1.0f : 0.0f;
    float my0 = (y0 >= 0 && y0 < IMG_H) ? 1.0f : 0.0f;
    float my1 = (y1 >= 0 && y1 < IMG_H) ? 1.0f : 0.0f;
    float w00 = wx0 * wy0 * mx0 * my0 * valid;
    float w10 = wx1 * wy0 * mx1 * my0 * valid;
    float w01 = wx0 * wy1 * mx0 * my1 * valid;
    float w11 = wx1 * wy1 * mx1 * my1 * valid;
    float h[HDIM];
#pragma unroll
    for (int j = 0; j < HDIM; ++j) h[j] = b1[j];
    const float* fb = feats + (size_t)b * FDIM * NPIX;
    const int p00 = y0c * IMG_W + x0c, p10 = y0c * IMG_W + x1c;
    const int p01 = y1c * IMG_W + x0c, p11 = y1c * IMG_W + x1c;
#pragma unroll 1
    for (int c = 0; c < FDIM; ++c) {
        const float* fp = fb + (size_t)c * NPIX;
        float fv = w00 * fp[p00] + w10 * fp[p10] + w01 * fp[p01] + w11 * fp[p11];
        const float* wr = W1 + (size_t)c * HDIM;
#pragma unroll
        for (int j = 0; j < HDIM; ++j) h[j] = fmaf(fv, wr[j], h[j]);
    }
#pragma unroll 1
    for (int m = 0; m < MSIZE; ++m) {
        float t = Bg[m * 3 + 0] * px + Bg[m * 3 + 1] * py + Bg[m * 3 + 2] * pz;
        float tf = t - floorf(t);
        float s = __builtin_amdgcn_sinf(tf);
        float c = __builtin_amdgcn_cosf(tf);
        const float* wsn = W1 + (size_t)(FDIM + m) * HDIM;
        const float* wcs = W1 + (size_t)(FDIM + MSIZE + m) * HDIM;
#pragma unroll
        for (int j = 0; j < HDIM; ++j)
            h[j] = fmaf(s, wsn[j], fmaf(c, wcs[j], h[j]));
    }
    float* myh = &hbuf[tid * 65];
#pragma unroll
    for (int j = 0; j < HDIM; ++j) myh[j] = fmaxf(h[j], 0.0f);
    float h2[HDIM];
#pragma unroll
    for (int j = 0; j < HDIM; ++j) h2[j] = b2[j];
#pragma unroll 1
    for (int i = 0; i < HDIM; ++i) {
        float hi = myh[i];
        const float* wr = W2 + (size_t)i * HDIM;
#pragma unroll
        for (int j = 0; j < HDIM; ++j) h2[j] = fmaf(hi, wr[j], h2[j]);
    }
#pragma unroll
    for (int j = 0; j < HDIM; ++j) myh[j] = fmaxf(h2[j], 0.0f);
#pragma unroll
    for (int j = 0; j < HDIM; ++j) h[j] = b3[j];
#pragma unroll 1
    for (int i = 0; i < HDIM; ++i) {
        float hi = myh[i];
        const float* wr = W3 + (size_t)i * HDIM;
#pragma unroll
        for (int j = 0; j < HDIM; ++j) h[j] = fmaf(hi, wr[j], h[j]);
    }
    float acc = b4[0];
#pragma unroll
    for (int j = 0; j < HDIM; ++j) acc = fmaf(fmaxf(h[j], 0.0f), W4[j], acc);
    out[gid] = acc;
}

extern "C" void kernel_launch(void* const* d_in, const int* in_sizes, int n_in,
                              void* d_out, int out_size, void* d_ws, size_t ws_size,
                              hipStream_t stream) {
    const float* feats = (const float*)d_in[0];
    const float* pts   = (const float*)d_in[1];
    const float* k     = (const float*)d_in[2];
    const float* rt    = (const float*)d_in[3];
    const float* Bg    = (const float*)d_in[4];
    const float* W1    = (const float*)d_in[5];
    const float* b1    = (const float*)d_in[6];
    const float* W2    = (const float*)d_in[7];
    const float* b2    = (const float*)d_in[8];
    const float* W3    = (const float*)d_in[9];
    const float* b3    = (const float*)d_in[10];
    const float* W4    = (const float*)d_in[11];
    const float* b4    = (const float*)d_in[12];
    float* out = (float*)d_out;

    const size_t gBytes = (size_t)NB * NPIX * HDIM * sizeof(_Float16);
    const size_t need = G_BYTE_OFF + gBytes;   // ~3.26 MB

    if (ws_size >= need) {
        _Float16* wf = (_Float16*)d_ws;
        _Float16* Gp = (_Float16*)((char*)d_ws + G_BYTE_OFF);
        pack_kernel<<<13, 256, 0, stream>>>(W1, W2, W3, Bg, wf);
        feat2g<<<NB * NPIX / 16 / 4, 256, 0, stream>>>(feats, wf, Gp);
        decoder_mfma8<<<NB * NPTS / 256, 256, 0, stream>>>(Gp, pts, k, rt, wf,
                                                           b1, b2, b3, W4, b4, out);
    } else {
        decoder_valu<<<NB * NPTS / 64, 64, 0, stream>>>(feats, pts, k, rt, Bg,
                                                        W1, b1, W2, b2, W3, b3, W4, b4, out);
    }
}